// Round 6
// baseline (439.875 us; speedup 1.0000x reference)
//
#include <hip/hip_runtime.h>

#define NHEADS 4
#define NEG_SLOPE 0.2f
#define EPS_LN 1e-5f

// ---------------- CSR build ----------------
__global__ __launch_bounds__(256) void k_init_deg(int* __restrict__ deg, int n) {
    int i = blockIdx.x * 256 + threadIdx.x;
    if (i < n) deg[i] = 1;  // self-loop
}

__global__ __launch_bounds__(256) void k_count(const int* __restrict__ dst, int* __restrict__ deg, int e) {
    int i = blockIdx.x * 256 + threadIdx.x;
    if (i < e) atomicAdd(&deg[dst[i]], 1);
}

__global__ __launch_bounds__(256) void k_scan1(const int* __restrict__ deg, int* __restrict__ rs,
                                               int* __restrict__ bsum, int n) {
    __shared__ int tmp[256];
    int tx = threadIdx.x;
    int i = blockIdx.x * 256 + tx;
    int v = (i < n) ? deg[i] : 0;
    tmp[tx] = v;
    __syncthreads();
    for (int off = 1; off < 256; off <<= 1) {
        int t = (tx >= off) ? tmp[tx - off] : 0;
        __syncthreads();
        tmp[tx] += t;
        __syncthreads();
    }
    if (i < n) rs[i] = tmp[tx] - v;
    if (tx == 255) bsum[blockIdx.x] = tmp[255];
}

__global__ __launch_bounds__(256) void k_scan2(int* __restrict__ bsum, int nb) {
    __shared__ int tmp[256];
    int tx = threadIdx.x;
    int v = (tx < nb) ? bsum[tx] : 0;
    tmp[tx] = v;
    __syncthreads();
    for (int off = 1; off < 256; off <<= 1) {
        int t = (tx >= off) ? tmp[tx - off] : 0;
        __syncthreads();
        tmp[tx] += t;
        __syncthreads();
    }
    if (tx < nb) bsum[tx] = tmp[tx] - v;
}

__global__ __launch_bounds__(256) void k_scan3(int* __restrict__ rs, int* __restrict__ cur,
                                               const int* __restrict__ bsum, int n, int total) {
    int i = blockIdx.x * 256 + threadIdx.x;
    if (i < n) {
        int r = rs[i] + bsum[blockIdx.x];
        rs[i] = r;
        cur[i] = r;
    }
    if (i == 0) rs[n] = total;
}

__global__ __launch_bounds__(256) void k_scatter(const int* __restrict__ src, const int* __restrict__ dst,
                                                 int* __restrict__ cur, int* __restrict__ col, int e, int n) {
    int i = blockIdx.x * 256 + threadIdx.x;
    if (i < e + n) {
        int s, d;
        if (i < e) { s = src[i]; d = dst[i]; }
        else       { s = i - e;  d = i - e;  }
        int p = atomicAdd(&cur[d], 1);
        col[p] = s;
    }
}

__device__ __forceinline__ unsigned pack_bf16(float a, float b) {
    unsigned ua = __float_as_uint(a); ua += 0x7fffu + ((ua >> 16) & 1u);
    unsigned ub = __float_as_uint(b); ub += 0x7fffu + ((ub >> 16) & 1u);
    return (ua >> 16) | (ub & 0xffff0000u);
}

// ---------------- 128x128-tile GEMM (fp32) -> bf16 h + fused attention coefficients ----------------
// C = A[M,K] @ B[K,256]; grid (ceil(M/128), 2); blockIdx.y picks a 128-col slab = 2 heads.
// 8x8 acc per thread: per k-step 4 ds_read_b128 vs 64 FMA. Thread tx covers 8 cols,
// all inside one head (myhead = 2*y + (tx>>3)); es/ed reduced over the 8-lane (tx&7) group.
__global__ __launch_bounds__(256) void k_gemm_gat(const float* __restrict__ A, const float* __restrict__ B,
                                                  const float* __restrict__ asrc, const float* __restrict__ adst,
                                                  unsigned* __restrict__ Hb, float* __restrict__ es,
                                                  float* __restrict__ ed, int M, int K) {
    __shared__ float As[16][136];   // [k][m]
    __shared__ float Bs[16][136];   // [k][n]
    int tid = threadIdx.x;
    int m0 = blockIdx.x * 128;
    int n0 = blockIdx.y * 128;
    int ty = tid >> 4, tx = tid & 15;
    int ar = tid >> 1;            // A-stage row 0..127
    int ak = (tid & 1) * 8;       // A-stage k base (0 or 8)
    int bk = tid >> 4;            // B-stage k row 0..15
    int bn = (tid & 15) * 8;      // B-stage col base
    float acc[8][8] = {};
    for (int k0 = 0; k0 < K; k0 += 16) {
        float4 a0 = make_float4(0.f, 0.f, 0.f, 0.f), a1 = a0;
        int am = m0 + ar;
        if (am < M) {
            a0 = *(const float4*)&A[(size_t)am * K + k0 + ak];
            a1 = *(const float4*)&A[(size_t)am * K + k0 + ak + 4];
        }
        As[ak + 0][ar] = a0.x; As[ak + 1][ar] = a0.y; As[ak + 2][ar] = a0.z; As[ak + 3][ar] = a0.w;
        As[ak + 4][ar] = a1.x; As[ak + 5][ar] = a1.y; As[ak + 6][ar] = a1.z; As[ak + 7][ar] = a1.w;
        *(float4*)&Bs[bk][bn]     = *(const float4*)&B[(size_t)(k0 + bk) * 256 + n0 + bn];
        *(float4*)&Bs[bk][bn + 4] = *(const float4*)&B[(size_t)(k0 + bk) * 256 + n0 + bn + 4];
        __syncthreads();
#pragma unroll
        for (int k = 0; k < 16; k++) {
            float4 x0 = *(const float4*)&As[k][ty * 8];
            float4 x1 = *(const float4*)&As[k][ty * 8 + 4];
            float4 y0 = *(const float4*)&Bs[k][tx * 8];
            float4 y1 = *(const float4*)&Bs[k][tx * 8 + 4];
            float av[8] = {x0.x, x0.y, x0.z, x0.w, x1.x, x1.y, x1.z, x1.w};
            float bv[8] = {y0.x, y0.y, y0.z, y0.w, y1.x, y1.y, y1.z, y1.w};
#pragma unroll
            for (int i = 0; i < 8; i++)
#pragma unroll
                for (int j = 0; j < 8; j++)
                    acc[i][j] += av[i] * bv[j];
        }
        __syncthreads();
    }
    // epilogue: es/ed per head (fp32-exact) + bf16 h write
    int myhead = blockIdx.y * 2 + (tx >> 3);
    int hc8 = (tx & 7) * 8;       // head-local col base
    float av0[8], dv0[8];
#pragma unroll
    for (int j = 0; j < 8; j++) {
        av0[j] = asrc[myhead * 64 + hc8 + j];
        dv0[j] = adst[myhead * 64 + hc8 + j];
    }
#pragma unroll
    for (int i = 0; i < 8; i++) {
        int m = m0 + ty * 8 + i;
        float se = 0.f, sd = 0.f;
#pragma unroll
        for (int j = 0; j < 8; j++) { se += acc[i][j] * av0[j]; sd += acc[i][j] * dv0[j]; }
        se += __shfl_xor(se, 1, 64); sd += __shfl_xor(sd, 1, 64);
        se += __shfl_xor(se, 2, 64); sd += __shfl_xor(sd, 2, 64);
        se += __shfl_xor(se, 4, 64); sd += __shfl_xor(sd, 4, 64);
        if (m < M) {
            uint4 p;
            p.x = pack_bf16(acc[i][0], acc[i][1]);
            p.y = pack_bf16(acc[i][2], acc[i][3]);
            p.z = pack_bf16(acc[i][4], acc[i][5]);
            p.w = pack_bf16(acc[i][6], acc[i][7]);
            *(uint4*)&Hb[(size_t)m * 128 + myhead * 32 + (tx & 7) * 4] = p;
            if ((tx & 7) == 0) { es[m * 4 + myhead] = se; ed[m * 4 + myhead] = sd; }
        }
    }
}

// ---------------- 128x128-tile fp32 GEMM with bias (output projection) ----------------
__global__ __launch_bounds__(256) void k_gemm(const float* __restrict__ A, const float* __restrict__ B,
                                              const float* __restrict__ bias, float* __restrict__ C,
                                              int M, int N, int K) {
    __shared__ float As[16][136];
    __shared__ float Bs[16][136];
    int tid = threadIdx.x;
    int m0 = blockIdx.x * 128, n0 = blockIdx.y * 128;
    int ty = tid >> 4, tx = tid & 15;
    int ar = tid >> 1;
    int ak = (tid & 1) * 8;
    int bk = tid >> 4;
    int bn = (tid & 15) * 8;
    float acc[8][8] = {};
    for (int k0 = 0; k0 < K; k0 += 16) {
        float4 a0 = make_float4(0.f, 0.f, 0.f, 0.f), a1 = a0;
        int am = m0 + ar;
        if (am < M) {
            a0 = *(const float4*)&A[(size_t)am * K + k0 + ak];
            a1 = *(const float4*)&A[(size_t)am * K + k0 + ak + 4];
        }
        As[ak + 0][ar] = a0.x; As[ak + 1][ar] = a0.y; As[ak + 2][ar] = a0.z; As[ak + 3][ar] = a0.w;
        As[ak + 4][ar] = a1.x; As[ak + 5][ar] = a1.y; As[ak + 6][ar] = a1.z; As[ak + 7][ar] = a1.w;
        *(float4*)&Bs[bk][bn]     = *(const float4*)&B[(size_t)(k0 + bk) * N + n0 + bn];
        *(float4*)&Bs[bk][bn + 4] = *(const float4*)&B[(size_t)(k0 + bk) * N + n0 + bn + 4];
        __syncthreads();
#pragma unroll
        for (int k = 0; k < 16; k++) {
            float4 x0 = *(const float4*)&As[k][ty * 8];
            float4 x1 = *(const float4*)&As[k][ty * 8 + 4];
            float4 y0 = *(const float4*)&Bs[k][tx * 8];
            float4 y1 = *(const float4*)&Bs[k][tx * 8 + 4];
            float av[8] = {x0.x, x0.y, x0.z, x0.w, x1.x, x1.y, x1.z, x1.w};
            float bv[8] = {y0.x, y0.y, y0.z, y0.w, y1.x, y1.y, y1.z, y1.w};
#pragma unroll
            for (int i = 0; i < 8; i++)
#pragma unroll
                for (int j = 0; j < 8; j++)
                    acc[i][j] += av[i] * bv[j];
        }
        __syncthreads();
    }
    int nbase = n0 + tx * 8;
    float4 bia0 = *(const float4*)&bias[nbase];
    float4 bia1 = *(const float4*)&bias[nbase + 4];
#pragma unroll
    for (int i = 0; i < 8; i++) {
        int m = m0 + ty * 8 + i;
        if (m < M) {
            float4 r0, r1;
            r0.x = acc[i][0] + bia0.x; r0.y = acc[i][1] + bia0.y;
            r0.z = acc[i][2] + bia0.z; r0.w = acc[i][3] + bia0.w;
            r1.x = acc[i][4] + bia1.x; r1.y = acc[i][5] + bia1.y;
            r1.z = acc[i][6] + bia1.z; r1.w = acc[i][7] + bia1.w;
            *(float4*)&C[(size_t)m * N + nbase]     = r0;
            *(float4*)&C[(size_t)m * N + nbase + 4] = r1;
        }
    }
}

// ---------------- fused GAT aggregate (bf16 gather) + head-mean + bias + LN + ReLU ----------------
// one wave per destination node; lane = (head, channel-quad). Unroll-4 with hoisted
// loads: 4 independent col->(es,Hb) chains in flight per wave for gather MLP.
__global__ __launch_bounds__(256) void k_gat_aggregate(const unsigned* __restrict__ Hb, const float* __restrict__ es,
                                                       const float* __restrict__ ed, const int* __restrict__ rs,
                                                       const int* __restrict__ col, const float* __restrict__ b,
                                                       const float* __restrict__ g, const float* __restrict__ be,
                                                       float* __restrict__ out, int n) {
    int node = blockIdx.x * 4 + (threadIdx.x >> 6);
    int lane = threadIdx.x & 63;
    if (node >= n) return;
    int head = lane >> 4;
    int cp = lane & 15;
    float edv = ed[node * 4 + head];
    float acc0 = 0.f, acc1 = 0.f, acc2 = 0.f, acc3 = 0.f, den = 0.f;
    int i0 = rs[node], i1 = rs[node + 1];
    int i = i0;
    for (; i + 3 < i1; i += 4) {
        int s0 = col[i], s1 = col[i + 1], s2 = col[i + 2], s3 = col[i + 3];
        float e0 = es[s0 * 4 + head];
        float e1 = es[s1 * 4 + head];
        float e2 = es[s2 * 4 + head];
        float e3 = es[s3 * 4 + head];
        uint2 u0 = *(const uint2*)&Hb[(size_t)s0 * 128 + lane * 2];
        uint2 u1 = *(const uint2*)&Hb[(size_t)s1 * 128 + lane * 2];
        uint2 u2 = *(const uint2*)&Hb[(size_t)s2 * 128 + lane * 2];
        uint2 u3 = *(const uint2*)&Hb[(size_t)s3 * 128 + lane * 2];
        e0 += edv; e1 += edv; e2 += edv; e3 += edv;
        e0 = fmaxf(e0, NEG_SLOPE * e0);
        e1 = fmaxf(e1, NEG_SLOPE * e1);
        e2 = fmaxf(e2, NEG_SLOPE * e2);
        e3 = fmaxf(e3, NEG_SLOPE * e3);
        float w0 = __expf(e0), w1 = __expf(e1), w2 = __expf(e2), w3 = __expf(e3);
        acc0 += w0 * __uint_as_float(u0.x << 16);
        acc1 += w0 * __uint_as_float(u0.x & 0xffff0000u);
        acc2 += w0 * __uint_as_float(u0.y << 16);
        acc3 += w0 * __uint_as_float(u0.y & 0xffff0000u);
        acc0 += w1 * __uint_as_float(u1.x << 16);
        acc1 += w1 * __uint_as_float(u1.x & 0xffff0000u);
        acc2 += w1 * __uint_as_float(u1.y << 16);
        acc3 += w1 * __uint_as_float(u1.y & 0xffff0000u);
        acc0 += w2 * __uint_as_float(u2.x << 16);
        acc1 += w2 * __uint_as_float(u2.x & 0xffff0000u);
        acc2 += w2 * __uint_as_float(u2.y << 16);
        acc3 += w2 * __uint_as_float(u2.y & 0xffff0000u);
        acc0 += w3 * __uint_as_float(u3.x << 16);
        acc1 += w3 * __uint_as_float(u3.x & 0xffff0000u);
        acc2 += w3 * __uint_as_float(u3.y << 16);
        acc3 += w3 * __uint_as_float(u3.y & 0xffff0000u);
        den += w0 + w1 + w2 + w3;
    }
    for (; i < i1; i++) {
        int s0 = col[i];
        float e0 = es[s0 * 4 + head] + edv;
        uint2 u0 = *(const uint2*)&Hb[(size_t)s0 * 128 + lane * 2];
        e0 = fmaxf(e0, NEG_SLOPE * e0);
        float w0 = __expf(e0);
        acc0 += w0 * __uint_as_float(u0.x << 16);
        acc1 += w0 * __uint_as_float(u0.x & 0xffff0000u);
        acc2 += w0 * __uint_as_float(u0.y << 16);
        acc3 += w0 * __uint_as_float(u0.y & 0xffff0000u);
        den += w0;
    }
    // softmax-normalize own head, then mean over heads via xor-16/32 butterflies
    float rd = 1.f / den;
    float r0 = acc0 * rd, r1 = acc1 * rd, r2 = acc2 * rd, r3 = acc3 * rd;
    r0 += __shfl_xor(r0, 16, 64); r1 += __shfl_xor(r1, 16, 64);
    r2 += __shfl_xor(r2, 16, 64); r3 += __shfl_xor(r3, 16, 64);
    r0 += __shfl_xor(r0, 32, 64); r1 += __shfl_xor(r1, 32, 64);
    r2 += __shfl_xor(r2, 32, 64); r3 += __shfl_xor(r3, 32, 64);
    float4 bb = *(const float4*)&b[cp * 4];
    float v0 = 0.25f * r0 + bb.x;
    float v1 = 0.25f * r1 + bb.y;
    float v2 = 0.25f * r2 + bb.z;
    float v3 = 0.25f * r3 + bb.w;
    // LayerNorm over 64 channels: reduce within the 16-lane head group (groups identical)
    float s = v0 + v1 + v2 + v3;
    float q = v0 * v0 + v1 * v1 + v2 * v2 + v3 * v3;
    for (int off = 1; off < 16; off <<= 1) {
        s += __shfl_xor(s, off, 64);
        q += __shfl_xor(q, off, 64);
    }
    float mean = s * (1.f / 64.f);
    float var = q * (1.f / 64.f) - mean * mean;
    float rinv = rsqrtf(var + EPS_LN);
    float4 gg = *(const float4*)&g[cp * 4];
    float4 ee = *(const float4*)&be[cp * 4];
    if (head == 0) {
        float4 y;
        y.x = fmaxf((v0 - mean) * rinv * gg.x + ee.x, 0.f);
        y.y = fmaxf((v1 - mean) * rinv * gg.y + ee.y, 0.f);
        y.z = fmaxf((v2 - mean) * rinv * gg.z + ee.z, 0.f);
        y.w = fmaxf((v3 - mean) * rinv * gg.w + ee.w, 0.f);
        *(float4*)&out[(size_t)node * 64 + cp * 4] = y;
    }
}

// ---------------- launch ----------------
extern "C" void kernel_launch(void* const* d_in, const int* in_sizes, int n_in,
                              void* d_out, int out_size, void* d_ws, size_t ws_size,
                              hipStream_t stream) {
    const float* x     = (const float*)d_in[0];
    const int*   eidx  = (const int*)d_in[1];
    const float* W1    = (const float*)d_in[2];
    const float* asrc1 = (const float*)d_in[3];
    const float* adst1 = (const float*)d_in[4];
    const float* b1    = (const float*)d_in[5];
    const float* g1    = (const float*)d_in[6];
    const float* be1   = (const float*)d_in[7];
    const float* W2    = (const float*)d_in[8];
    const float* asrc2 = (const float*)d_in[9];
    const float* adst2 = (const float*)d_in[10];
    const float* b2    = (const float*)d_in[11];
    const float* g2    = (const float*)d_in[12];
    const float* be2   = (const float*)d_in[13];
    const float* Wo    = (const float*)d_in[14];
    const float* bo    = (const float*)d_in[15];

    const int N = in_sizes[0] / 128;
    const int E = in_sizes[1] / 2;
    const int* srcp = eidx;
    const int* dstp = eidx + E;

    // workspace layout
    unsigned* hb   = (unsigned*)d_ws;                       // [N*128] bf16x2 (h1, then h3)
    float* h_small = (float*)(hb + (size_t)N * 128);        // [N,64] fp32 (h2, then h4)
    float* es      = h_small + (size_t)N * 64;              // [N,4]
    float* ed      = es + (size_t)N * 4;                    // [N,4]
    int* deg       = (int*)(ed + (size_t)N * 4);            // [N]
    int* rowstart  = deg + N;                               // [N+1]
    int* cursor    = rowstart + (N + 1);                    // [N]
    int* colarr    = cursor + N;                            // [E+N]
    int* bsum      = colarr + (size_t)(E + N);              // [<=256]

    const int nb = (N + 255) / 256;
    const int nwb = (N + 3) / 4;
    const int mt128 = (N + 127) / 128;

    // CSR build
    k_init_deg<<<nb, 256, 0, stream>>>(deg, N);
    k_count<<<(E + 255) / 256, 256, 0, stream>>>(dstp, deg, E);
    k_scan1<<<nb, 256, 0, stream>>>(deg, rowstart, bsum, N);
    k_scan2<<<1, 256, 0, stream>>>(bsum, nb);
    k_scan3<<<nb, 256, 0, stream>>>(rowstart, cursor, bsum, N, E + N);
    k_scatter<<<(E + N + 255) / 256, 256, 0, stream>>>(srcp, dstp, cursor, colarr, E, N);

    // layer 1: GEMM (128x128 tiles, 2 heads per y-block) + fused attn coef
    k_gemm_gat<<<dim3(mt128, 2), 256, 0, stream>>>(x, W1, asrc1, adst1, hb, es, ed, N, 128);
    k_gat_aggregate<<<nwb, 256, 0, stream>>>(hb, es, ed, rowstart, colarr, b1, g1, be1, h_small, N);

    // layer 2
    k_gemm_gat<<<dim3(mt128, 2), 256, 0, stream>>>(h_small, W2, asrc2, adst2, hb, es, ed, N, 64);
    k_gat_aggregate<<<nwb, 256, 0, stream>>>(hb, es, ed, rowstart, colarr, b2, g2, be2, h_small, N);

    // output projection (fp32, 128x128 tile)
    k_gemm<<<dim3(mt128, 1), 256, 0, stream>>>(h_small, Wo, bo, (float*)d_out, N, 128, 64);
}

// Round 7
// 433.288 us; speedup vs baseline: 1.0152x; 1.0152x over previous
//
#include <hip/hip_runtime.h>

#define NHEADS 4
#define NEG_SLOPE 0.2f
#define EPS_LN 1e-5f

// ---------------- CSR build ----------------
__global__ __launch_bounds__(256) void k_init_deg(int* __restrict__ deg, int n) {
    int i = blockIdx.x * 256 + threadIdx.x;
    if (i < n) deg[i] = 1;  // self-loop
}

__global__ __launch_bounds__(256) void k_count(const int* __restrict__ dst, int* __restrict__ deg, int e) {
    int i = blockIdx.x * 256 + threadIdx.x;
    if (i < e) atomicAdd(&deg[dst[i]], 1);
}

__global__ __launch_bounds__(256) void k_scan1(const int* __restrict__ deg, int* __restrict__ rs,
                                               int* __restrict__ bsum, int n) {
    __shared__ int tmp[256];
    int tx = threadIdx.x;
    int i = blockIdx.x * 256 + tx;
    int v = (i < n) ? deg[i] : 0;
    tmp[tx] = v;
    __syncthreads();
    for (int off = 1; off < 256; off <<= 1) {
        int t = (tx >= off) ? tmp[tx - off] : 0;
        __syncthreads();
        tmp[tx] += t;
        __syncthreads();
    }
    if (i < n) rs[i] = tmp[tx] - v;
    if (tx == 255) bsum[blockIdx.x] = tmp[255];
}

__global__ __launch_bounds__(256) void k_scan2(int* __restrict__ bsum, int nb) {
    __shared__ int tmp[256];
    int tx = threadIdx.x;
    int v = (tx < nb) ? bsum[tx] : 0;
    tmp[tx] = v;
    __syncthreads();
    for (int off = 1; off < 256; off <<= 1) {
        int t = (tx >= off) ? tmp[tx - off] : 0;
        __syncthreads();
        tmp[tx] += t;
        __syncthreads();
    }
    if (tx < nb) bsum[tx] = tmp[tx] - v;
}

__global__ __launch_bounds__(256) void k_scan3(int* __restrict__ rs, int* __restrict__ cur,
                                               const int* __restrict__ bsum, int n, int total) {
    int i = blockIdx.x * 256 + threadIdx.x;
    if (i < n) {
        int r = rs[i] + bsum[blockIdx.x];
        rs[i] = r;
        cur[i] = r;
    }
    if (i == 0) rs[n] = total;
}

__global__ __launch_bounds__(256) void k_scatter(const int* __restrict__ src, const int* __restrict__ dst,
                                                 int* __restrict__ cur, int* __restrict__ col, int e, int n) {
    int i = blockIdx.x * 256 + threadIdx.x;
    if (i < e + n) {
        int s, d;
        if (i < e) { s = src[i]; d = dst[i]; }
        else       { s = i - e;  d = i - e;  }
        int p = atomicAdd(&cur[d], 1);
        col[p] = s;
    }
}

__device__ __forceinline__ unsigned pack_bf16(float a, float b) {
    unsigned ua = __float_as_uint(a); ua += 0x7fffu + ((ua >> 16) & 1u);
    unsigned ub = __float_as_uint(b); ub += 0x7fffu + ((ub >> 16) & 1u);
    return (ua >> 16) | (ub & 0xffff0000u);
}

// ---------------- 128x128-tile GEMM (fp32) -> bf16 h + fused attention coefficients ----------------
// C = A[M,K] @ B[K,256]; grid (ceil(M/128), 2); blockIdx.y picks a 128-col slab = heads {2y, 2y+1}.
// 8x8 acc per thread as FOUR 4x4 QUADRANTS: rows {ty*4, 64+ty*4}, cols {tx*4, 64+tx*4}.
// All LDS reads are float4 at stride-4 lane addresses -> 2-way bank aliasing (free).
// Column half 0 = head 2y, half 1 = head 2y+1 (64-col boundary = head boundary).
__global__ __launch_bounds__(256) void k_gemm_gat(const float* __restrict__ A, const float* __restrict__ B,
                                                  const float* __restrict__ asrc, const float* __restrict__ adst,
                                                  unsigned* __restrict__ Hb, float* __restrict__ es,
                                                  float* __restrict__ ed, int M, int K) {
    __shared__ float As[16][132];   // [k][m], stride 132 (16B-aligned, non-pow2)
    __shared__ float Bs[16][132];   // [k][n]
    int tid = threadIdx.x;
    int m0 = blockIdx.x * 128;
    int n0 = blockIdx.y * 128;
    int ty = tid >> 4, tx = tid & 15;
    int ar = tid >> 1;            // A-stage row 0..127
    int ak = (tid & 1) * 8;       // A-stage k base (0 or 8)
    int bk = tid >> 4;            // B-stage k row 0..15
    int bn = (tid & 15) * 4;      // B-stage col base (stride-4: 2-way, free)
    float acc[8][8] = {};         // [rowhalf*4+i][colhalf*4+j]
    for (int k0 = 0; k0 < K; k0 += 16) {
        float4 a0 = make_float4(0.f, 0.f, 0.f, 0.f), a1 = a0;
        int am = m0 + ar;
        if (am < M) {
            a0 = *(const float4*)&A[(size_t)am * K + k0 + ak];
            a1 = *(const float4*)&A[(size_t)am * K + k0 + ak + 4];
        }
        As[ak + 0][ar] = a0.x; As[ak + 1][ar] = a0.y; As[ak + 2][ar] = a0.z; As[ak + 3][ar] = a0.w;
        As[ak + 4][ar] = a1.x; As[ak + 5][ar] = a1.y; As[ak + 6][ar] = a1.z; As[ak + 7][ar] = a1.w;
        *(float4*)&Bs[bk][bn]      = *(const float4*)&B[(size_t)(k0 + bk) * 256 + n0 + bn];
        *(float4*)&Bs[bk][bn + 64] = *(const float4*)&B[(size_t)(k0 + bk) * 256 + n0 + bn + 64];
        __syncthreads();
#pragma unroll
        for (int k = 0; k < 16; k++) {
            float4 x0 = *(const float4*)&As[k][ty * 4];        // rows ty*4..+3
            float4 x1 = *(const float4*)&As[k][64 + ty * 4];   // rows 64+ty*4..+3
            float4 y0 = *(const float4*)&Bs[k][tx * 4];        // cols tx*4..+3 (head lo)
            float4 y1 = *(const float4*)&Bs[k][64 + tx * 4];   // cols 64+tx*4..+3 (head hi)
            float av[8] = {x0.x, x0.y, x0.z, x0.w, x1.x, x1.y, x1.z, x1.w};
            float bv[8] = {y0.x, y0.y, y0.z, y0.w, y1.x, y1.y, y1.z, y1.w};
#pragma unroll
            for (int i = 0; i < 8; i++)
#pragma unroll
                for (int j = 0; j < 8; j++)
                    acc[i][j] += av[i] * bv[j];
        }
        __syncthreads();
    }
    // epilogue: es/ed per head (fp32-exact, butterfly over tx bits 1/2/4/8) + bf16 h write
    int h0 = blockIdx.y * 2, h1 = h0 + 1;
    float a0v[4], d0v[4], a1v[4], d1v[4];
#pragma unroll
    for (int j = 0; j < 4; j++) {
        a0v[j] = asrc[h0 * 64 + tx * 4 + j];
        d0v[j] = adst[h0 * 64 + tx * 4 + j];
        a1v[j] = asrc[h1 * 64 + tx * 4 + j];
        d1v[j] = adst[h1 * 64 + tx * 4 + j];
    }
#pragma unroll
    for (int r = 0; r < 2; r++) {
#pragma unroll
        for (int i = 0; i < 4; i++) {
            int ai = r * 4 + i;
            int m = m0 + r * 64 + ty * 4 + i;
            float se0 = 0.f, sd0 = 0.f, se1 = 0.f, sd1 = 0.f;
#pragma unroll
            for (int j = 0; j < 4; j++) {
                se0 += acc[ai][j] * a0v[j];     sd0 += acc[ai][j] * d0v[j];
                se1 += acc[ai][4 + j] * a1v[j]; sd1 += acc[ai][4 + j] * d1v[j];
            }
#pragma unroll
            for (int off = 1; off < 16; off <<= 1) {
                se0 += __shfl_xor(se0, off, 64); sd0 += __shfl_xor(sd0, off, 64);
                se1 += __shfl_xor(se1, off, 64); sd1 += __shfl_xor(sd1, off, 64);
            }
            if (m < M) {
                uint2 p0, p1;
                p0.x = pack_bf16(acc[ai][0], acc[ai][1]);
                p0.y = pack_bf16(acc[ai][2], acc[ai][3]);
                p1.x = pack_bf16(acc[ai][4], acc[ai][5]);
                p1.y = pack_bf16(acc[ai][6], acc[ai][7]);
                *(uint2*)&Hb[(size_t)m * 128 + h0 * 32 + tx * 2] = p0;
                *(uint2*)&Hb[(size_t)m * 128 + h1 * 32 + tx * 2] = p1;
                if (tx == 0) {
                    es[m * 4 + h0] = se0; ed[m * 4 + h0] = sd0;
                    es[m * 4 + h1] = se1; ed[m * 4 + h1] = sd1;
                }
            }
        }
    }
}

// ---------------- 128x128-tile fp32 GEMM with bias (output projection) ----------------
// Same quadrant micro-tile as k_gemm_gat.
__global__ __launch_bounds__(256) void k_gemm(const float* __restrict__ A, const float* __restrict__ B,
                                              const float* __restrict__ bias, float* __restrict__ C,
                                              int M, int N, int K) {
    __shared__ float As[16][132];
    __shared__ float Bs[16][132];
    int tid = threadIdx.x;
    int m0 = blockIdx.x * 128, n0 = blockIdx.y * 128;
    int ty = tid >> 4, tx = tid & 15;
    int ar = tid >> 1;
    int ak = (tid & 1) * 8;
    int bk = tid >> 4;
    int bn = (tid & 15) * 4;
    float acc[8][8] = {};
    for (int k0 = 0; k0 < K; k0 += 16) {
        float4 a0 = make_float4(0.f, 0.f, 0.f, 0.f), a1 = a0;
        int am = m0 + ar;
        if (am < M) {
            a0 = *(const float4*)&A[(size_t)am * K + k0 + ak];
            a1 = *(const float4*)&A[(size_t)am * K + k0 + ak + 4];
        }
        As[ak + 0][ar] = a0.x; As[ak + 1][ar] = a0.y; As[ak + 2][ar] = a0.z; As[ak + 3][ar] = a0.w;
        As[ak + 4][ar] = a1.x; As[ak + 5][ar] = a1.y; As[ak + 6][ar] = a1.z; As[ak + 7][ar] = a1.w;
        *(float4*)&Bs[bk][bn]      = *(const float4*)&B[(size_t)(k0 + bk) * N + n0 + bn];
        *(float4*)&Bs[bk][bn + 64] = *(const float4*)&B[(size_t)(k0 + bk) * N + n0 + bn + 64];
        __syncthreads();
#pragma unroll
        for (int k = 0; k < 16; k++) {
            float4 x0 = *(const float4*)&As[k][ty * 4];
            float4 x1 = *(const float4*)&As[k][64 + ty * 4];
            float4 y0 = *(const float4*)&Bs[k][tx * 4];
            float4 y1 = *(const float4*)&Bs[k][64 + tx * 4];
            float av[8] = {x0.x, x0.y, x0.z, x0.w, x1.x, x1.y, x1.z, x1.w};
            float bv[8] = {y0.x, y0.y, y0.z, y0.w, y1.x, y1.y, y1.z, y1.w};
#pragma unroll
            for (int i = 0; i < 8; i++)
#pragma unroll
                for (int j = 0; j < 8; j++)
                    acc[i][j] += av[i] * bv[j];
        }
        __syncthreads();
    }
    int nb0 = n0 + tx * 4, nb1 = n0 + 64 + tx * 4;
    float4 bia0 = *(const float4*)&bias[nb0];
    float4 bia1 = *(const float4*)&bias[nb1];
#pragma unroll
    for (int r = 0; r < 2; r++) {
#pragma unroll
        for (int i = 0; i < 4; i++) {
            int ai = r * 4 + i;
            int m = m0 + r * 64 + ty * 4 + i;
            if (m < M) {
                float4 r0, r1;
                r0.x = acc[ai][0] + bia0.x; r0.y = acc[ai][1] + bia0.y;
                r0.z = acc[ai][2] + bia0.z; r0.w = acc[ai][3] + bia0.w;
                r1.x = acc[ai][4] + bia1.x; r1.y = acc[ai][5] + bia1.y;
                r1.z = acc[ai][6] + bia1.z; r1.w = acc[ai][7] + bia1.w;
                *(float4*)&C[(size_t)m * N + nb0] = r0;
                *(float4*)&C[(size_t)m * N + nb1] = r1;
            }
        }
    }
}

// ---------------- fused GAT aggregate (bf16 gather) + head-mean + bias + LN + ReLU ----------------
// one wave per destination node; lane = (head, channel-quad). Unroll-4 with hoisted
// loads: 4 independent col->(es,Hb) chains in flight per wave for gather MLP.
__global__ __launch_bounds__(256) void k_gat_aggregate(const unsigned* __restrict__ Hb, const float* __restrict__ es,
                                                       const float* __restrict__ ed, const int* __restrict__ rs,
                                                       const int* __restrict__ col, const float* __restrict__ b,
                                                       const float* __restrict__ g, const float* __restrict__ be,
                                                       float* __restrict__ out, int n) {
    int node = blockIdx.x * 4 + (threadIdx.x >> 6);
    int lane = threadIdx.x & 63;
    if (node >= n) return;
    int head = lane >> 4;
    int cp = lane & 15;
    float edv = ed[node * 4 + head];
    float acc0 = 0.f, acc1 = 0.f, acc2 = 0.f, acc3 = 0.f, den = 0.f;
    int i0 = rs[node], i1 = rs[node + 1];
    int i = i0;
    for (; i + 3 < i1; i += 4) {
        int s0 = col[i], s1 = col[i + 1], s2 = col[i + 2], s3 = col[i + 3];
        float e0 = es[s0 * 4 + head];
        float e1 = es[s1 * 4 + head];
        float e2 = es[s2 * 4 + head];
        float e3 = es[s3 * 4 + head];
        uint2 u0 = *(const uint2*)&Hb[(size_t)s0 * 128 + lane * 2];
        uint2 u1 = *(const uint2*)&Hb[(size_t)s1 * 128 + lane * 2];
        uint2 u2 = *(const uint2*)&Hb[(size_t)s2 * 128 + lane * 2];
        uint2 u3 = *(const uint2*)&Hb[(size_t)s3 * 128 + lane * 2];
        e0 += edv; e1 += edv; e2 += edv; e3 += edv;
        e0 = fmaxf(e0, NEG_SLOPE * e0);
        e1 = fmaxf(e1, NEG_SLOPE * e1);
        e2 = fmaxf(e2, NEG_SLOPE * e2);
        e3 = fmaxf(e3, NEG_SLOPE * e3);
        float w0 = __expf(e0), w1 = __expf(e1), w2 = __expf(e2), w3 = __expf(e3);
        acc0 += w0 * __uint_as_float(u0.x << 16);
        acc1 += w0 * __uint_as_float(u0.x & 0xffff0000u);
        acc2 += w0 * __uint_as_float(u0.y << 16);
        acc3 += w0 * __uint_as_float(u0.y & 0xffff0000u);
        acc0 += w1 * __uint_as_float(u1.x << 16);
        acc1 += w1 * __uint_as_float(u1.x & 0xffff0000u);
        acc2 += w1 * __uint_as_float(u1.y << 16);
        acc3 += w1 * __uint_as_float(u1.y & 0xffff0000u);
        acc0 += w2 * __uint_as_float(u2.x << 16);
        acc1 += w2 * __uint_as_float(u2.x & 0xffff0000u);
        acc2 += w2 * __uint_as_float(u2.y << 16);
        acc3 += w2 * __uint_as_float(u2.y & 0xffff0000u);
        acc0 += w3 * __uint_as_float(u3.x << 16);
        acc1 += w3 * __uint_as_float(u3.x & 0xffff0000u);
        acc2 += w3 * __uint_as_float(u3.y << 16);
        acc3 += w3 * __uint_as_float(u3.y & 0xffff0000u);
        den += w0 + w1 + w2 + w3;
    }
    for (; i < i1; i++) {
        int s0 = col[i];
        float e0 = es[s0 * 4 + head] + edv;
        uint2 u0 = *(const uint2*)&Hb[(size_t)s0 * 128 + lane * 2];
        e0 = fmaxf(e0, NEG_SLOPE * e0);
        float w0 = __expf(e0);
        acc0 += w0 * __uint_as_float(u0.x << 16);
        acc1 += w0 * __uint_as_float(u0.x & 0xffff0000u);
        acc2 += w0 * __uint_as_float(u0.y << 16);
        acc3 += w0 * __uint_as_float(u0.y & 0xffff0000u);
        den += w0;
    }
    // softmax-normalize own head, then mean over heads via xor-16/32 butterflies
    float rd = 1.f / den;
    float r0 = acc0 * rd, r1 = acc1 * rd, r2 = acc2 * rd, r3 = acc3 * rd;
    r0 += __shfl_xor(r0, 16, 64); r1 += __shfl_xor(r1, 16, 64);
    r2 += __shfl_xor(r2, 16, 64); r3 += __shfl_xor(r3, 16, 64);
    r0 += __shfl_xor(r0, 32, 64); r1 += __shfl_xor(r1, 32, 64);
    r2 += __shfl_xor(r2, 32, 64); r3 += __shfl_xor(r3, 32, 64);
    float4 bb = *(const float4*)&b[cp * 4];
    float v0 = 0.25f * r0 + bb.x;
    float v1 = 0.25f * r1 + bb.y;
    float v2 = 0.25f * r2 + bb.z;
    float v3 = 0.25f * r3 + bb.w;
    // LayerNorm over 64 channels: reduce within the 16-lane head group (groups identical)
    float s = v0 + v1 + v2 + v3;
    float q = v0 * v0 + v1 * v1 + v2 * v2 + v3 * v3;
    for (int off = 1; off < 16; off <<= 1) {
        s += __shfl_xor(s, off, 64);
        q += __shfl_xor(q, off, 64);
    }
    float mean = s * (1.f / 64.f);
    float var = q * (1.f / 64.f) - mean * mean;
    float rinv = rsqrtf(var + EPS_LN);
    float4 gg = *(const float4*)&g[cp * 4];
    float4 ee = *(const float4*)&be[cp * 4];
    if (head == 0) {
        float4 y;
        y.x = fmaxf((v0 - mean) * rinv * gg.x + ee.x, 0.f);
        y.y = fmaxf((v1 - mean) * rinv * gg.y + ee.y, 0.f);
        y.z = fmaxf((v2 - mean) * rinv * gg.z + ee.z, 0.f);
        y.w = fmaxf((v3 - mean) * rinv * gg.w + ee.w, 0.f);
        *(float4*)&out[(size_t)node * 64 + cp * 4] = y;
    }
}

// ---------------- launch ----------------
extern "C" void kernel_launch(void* const* d_in, const int* in_sizes, int n_in,
                              void* d_out, int out_size, void* d_ws, size_t ws_size,
                              hipStream_t stream) {
    const float* x     = (const float*)d_in[0];
    const int*   eidx  = (const int*)d_in[1];
    const float* W1    = (const float*)d_in[2];
    const float* asrc1 = (const float*)d_in[3];
    const float* adst1 = (const float*)d_in[4];
    const float* b1    = (const float*)d_in[5];
    const float* g1    = (const float*)d_in[6];
    const float* be1   = (const float*)d_in[7];
    const float* W2    = (const float*)d_in[8];
    const float* asrc2 = (const float*)d_in[9];
    const float* adst2 = (const float*)d_in[10];
    const float* b2    = (const float*)d_in[11];
    const float* g2    = (const float*)d_in[12];
    const float* be2   = (const float*)d_in[13];
    const float* Wo    = (const float*)d_in[14];
    const float* bo    = (const float*)d_in[15];

    const int N = in_sizes[0] / 128;
    const int E = in_sizes[1] / 2;
    const int* srcp = eidx;
    const int* dstp = eidx + E;

    // workspace layout
    unsigned* hb   = (unsigned*)d_ws;                       // [N*128] bf16x2 (h1, then h3)
    float* h_small = (float*)(hb + (size_t)N * 128);        // [N,64] fp32 (h2, then h4)
    float* es      = h_small + (size_t)N * 64;              // [N,4]
    float* ed      = es + (size_t)N * 4;                    // [N,4]
    int* deg       = (int*)(ed + (size_t)N * 4);            // [N]
    int* rowstart  = deg + N;                               // [N+1]
    int* cursor    = rowstart + (N + 1);                    // [N]
    int* colarr    = cursor + N;                            // [E+N]
    int* bsum      = colarr + (size_t)(E + N);              // [<=256]

    const int nb = (N + 255) / 256;
    const int nwb = (N + 3) / 4;
    const int mt128 = (N + 127) / 128;

    // CSR build
    k_init_deg<<<nb, 256, 0, stream>>>(deg, N);
    k_count<<<(E + 255) / 256, 256, 0, stream>>>(dstp, deg, E);
    k_scan1<<<nb, 256, 0, stream>>>(deg, rowstart, bsum, N);
    k_scan2<<<1, 256, 0, stream>>>(bsum, nb);
    k_scan3<<<nb, 256, 0, stream>>>(rowstart, cursor, bsum, N, E + N);
    k_scatter<<<(E + N + 255) / 256, 256, 0, stream>>>(srcp, dstp, cursor, colarr, E, N);

    // layer 1: GEMM (128x128 tiles, 2 heads per y-block) + fused attn coef
    k_gemm_gat<<<dim3(mt128, 2), 256, 0, stream>>>(x, W1, asrc1, adst1, hb, es, ed, N, 128);
    k_gat_aggregate<<<nwb, 256, 0, stream>>>(hb, es, ed, rowstart, colarr, b1, g1, be1, h_small, N);

    // layer 2
    k_gemm_gat<<<dim3(mt128, 2), 256, 0, stream>>>(h_small, W2, asrc2, adst2, hb, es, ed, N, 64);
    k_gat_aggregate<<<nwb, 256, 0, stream>>>(hb, es, ed, rowstart, colarr, b2, g2, be2, h_small, N);

    // output projection (fp32, 128x128 tile)
    k_gemm<<<dim3(mt128, 1), 256, 0, stream>>>(h_small, Wo, bo, (float*)d_out, N, 128, 64);
}